// Round 3
// baseline (259.206 us; speedup 1.0000x reference)
//
#include <hip/hip_runtime.h>

// multihead self-attention: B=4 S=2048 D=1024 H=16 DK=64, causal, RoPE(theta=1e4)
// f16 pipeline, 4 dispatches:
//   cvt_all | QKV GEMM (m201-style 256^2 4-phase, RoPE fused) | transposed flash | out GEMM
//
// R3: R2's merged phase was the m196 "coarse split" anti-pattern (587 TF).
// This round is the proven m201 template in plain HIP:
//  - BM=BN=256, 512 thr / 8 waves (2Mx4N), per-wave 128x64, acc[8][4];
//    24 ds_read_b128 per 64 MFMA per tile (0.375 ratio vs R2's 0.5).
//  - 4 fine phases per K-tile: {reads || 1 half-tile glds stage || bar ||
//    lgkm0 || 16 MFMA || bar}; counted vmcnt(4) ONLY at phases 2 and 4
//    (never 0 in main loop; tail drains 0 at t=15).
//  - LDS 128 KB ring-2; k-halves as separate 16 KB planes (lane-linear glds
//    dest); in-plane row-pair XOR swizzle, bijection matched store/read,
//    conflict-free per 8-lane group, all ds_read offsets compile-time imm.
//  - bijective XCD swizzle (384=48x8, 128=16x8 blocks).

#define D_MODEL 1024
#define NH      16
#define DKH     64
#define SEQ     2048
#define BATCH   4
#define SCALE_LOG2 0.180336875461f   // (1/sqrt(64)) * log2(e)
#define ROPE_L2    0.41524101186092029f  // log2(1e4)/32

typedef _Float16 f16;
typedef _Float16 f16x8 __attribute__((ext_vector_type(8)));
typedef _Float16 f16x4 __attribute__((ext_vector_type(4)));
typedef __fp16   fp16x2n __attribute__((ext_vector_type(2)));
typedef float    f32x4 __attribute__((ext_vector_type(4)));
typedef unsigned short u16;
typedef unsigned int   u32;

__device__ __forceinline__ void glds16(const void* g, void* l) {
  __builtin_amdgcn_global_load_lds((const __attribute__((address_space(1))) void*)g,
                                   (__attribute__((address_space(3))) void*)l, 16, 0, 0);
}
__device__ __forceinline__ u32 pk(float a, float b) {
  union { fp16x2n h; u32 u; } c; c.h = __builtin_amdgcn_cvt_pkrtz(a, b); return c.u;
}

// ---------------- f32 -> f16 convert: x (8192 blocks) + 4 weights (1024 each) ----
__global__ void cvt_all(const float* __restrict__ x,
                        const float* __restrict__ w0, const float* __restrict__ w1,
                        const float* __restrict__ w2, const float* __restrict__ w3,
                        f16* __restrict__ xo, f16* __restrict__ o0, f16* __restrict__ o1,
                        f16* __restrict__ o2, f16* __restrict__ o3) {
  int blk = blockIdx.x;
  const float* src; f16* dst; int off;
  if (blk < 8192) { src = x; dst = xo; off = blk; }
  else {
    int t = blk - 8192; int w = t >> 10; off = t & 1023;
    switch (w) { case 0: src = w0; dst = o0; break;  case 1: src = w1; dst = o1; break;
                 case 2: src = w2; dst = o2; break;  default: src = w3; dst = o3; break; }
  }
  int i = (off * 256 + threadIdx.x) * 4;
  float4 v = *(const float4*)(src + i);
  uint2 o; o.x = pk(v.x, v.y); o.y = pk(v.z, v.w);
  *(uint2*)(dst + i) = o;
}

// ---- 256^2 deep-pipelined GEMM: C[M,N] = A[M,1024] * W[N,1024]^T ----
// LDS (131072 B dynamic):
//   A plane (buf,h): lds + buf*32768 + h*16384, 16 KB = 256 rows x 64 B (k-half)
//   B plane (buf,h): lds + 65536 + buf*32768 + h*16384
// Plane layout (16-B chunks, L = linear chunk 0..1023):
//   L = sr*8 + (r&1)*4 + (c ^ (sr&3)),  sr = r>>1, c = chunk-in-half (0..3)
// Store side: thread tid handles L0=tid (rows 0..127) and L1=tid+512 (rows
// 128..255, same c). Read side: row R (R&7-aligned bases), chunk quad ->
// offset sr*128 + pos*16, pos = (R&1)*4 + (quad ^ ((R>>1)&3)) — per-thread
// constant; every 8-lane group covers 8 distinct 16-B bank slots (conflict-free).
// Phase schedule per K-tile t (buf b=t&1, stage target b^1 = tile t+1):
//  p1: rd A(mg0,h0)x4 + B(h0)x4; stage A-h0; bar; lgkm0; 16 MFMA; bar
//  p2: rd A(mg1,h0)x4;           stage B-h0; bar; lgkm0; 16 MFMA; vmcnt(4); bar
//  p3: rd A(mg0,h1)x4 + B(h1)x4; stage A-h1; bar; lgkm0; 16 MFMA; bar
//  p4: rd A(mg1,h1)x4;           stage B-h1; bar; lgkm0; 16 MFMA; vmcnt(4); bar
// Steady state: 8 glds outstanding, vmcnt(4) drains exactly the 4 the next
// reads need. Prologue stages tile 0 (order A-h0,B-h0,A-h1,B-h1), vmcnt(4).
// Tail: t15 stages nothing, p2-wait = vmcnt(0), p4 = last (no wait).
#define VMW_(N) asm volatile("s_waitcnt vmcnt(" #N ")" ::: "memory")
#define VMW(N) VMW_(N)

template<int MODE, int CPX, int NBX>
__global__ __launch_bounds__(512, 2) void gemm256(const f16* __restrict__ A,
                                                  const f16* __restrict__ W,
                                                  void* __restrict__ C0,
                                                  void* __restrict__ C1,
                                                  void* __restrict__ C2,
                                                  const int* __restrict__ pos) {
  extern __shared__ char lds[];
  const int bid  = blockIdx.x;
  const int lin  = (bid & 7) * CPX + (bid >> 3);   // bijective XCD swizzle
  const int bx   = lin % NBX, by = lin / NBX;
  const int m0   = by * 256, n0 = bx * 256;
  const int tid  = threadIdx.x;
  const int wave = tid >> 6, lane = tid & 63;
  const int quad = lane >> 4, l16 = lane & 15;
  const int wr   = wave >> 2, wc = wave & 3;       // wave tile: rows wr*128, cols wc*64

  f32x4 acc[8][4];
#pragma unroll
  for (int i = 0; i < 8; ++i)
#pragma unroll
    for (int j = 0; j < 4; ++j) acc[i][j] = (f32x4){0.f, 0.f, 0.f, 0.f};

  // read bases (per-thread constant; all ds offsets are compile-time imm)
  const int posR = (l16 & 1) * 4 + (quad ^ ((l16 >> 1) & 3));
  const char* aRd = lds + wr * 8192 + (l16 >> 1) * 128 + posR * 16;
  const char* bRd = lds + 65536 + wc * 4096 + (l16 >> 1) * 128 + posR * 16;

  // stage roles: thread covers plane chunks L0=tid, L1=tid+512
  const int r0 = 2 * (tid >> 3) + ((tid & 7) >> 2);
  const int c0 = (tid & 3) ^ ((tid >> 3) & 3);
  const f16* pA0 = A + (size_t)(m0 + r0) * 1024 + c0 * 8;
  const f16* pA1 = pA0 + (size_t)128 * 1024;
  const f16* pB0 = W + (size_t)(n0 + r0) * 1024 + c0 * 8;
  const f16* pB1 = pB0 + (size_t)128 * 1024;
  char* const sdA = lds + (size_t)(tid & 448) * 16;
  char* const sdB = lds + 65536 + (size_t)(tid & 448) * 16;

#define ST_A(TB, H) do {                                                      \
    glds16(pA0 + (H) * 32, sdA + (TB) * 32768 + (H) * 16384);                 \
    glds16(pA1 + (H) * 32, sdA + (TB) * 32768 + (H) * 16384 + 8192);          \
  } while (0)
#define ST_B(TB, H) do {                                                      \
    glds16(pB0 + (H) * 32, sdB + (TB) * 32768 + (H) * 16384);                 \
    glds16(pB1 + (H) * 32, sdB + (TB) * 32768 + (H) * 16384 + 8192);          \
  } while (0)
#define RDA(BUF, H, MG) do { _Pragma("unroll")                                \
    for (int i_ = 0; i_ < 4; ++i_)                                            \
      af[i_] = *(const f16x8*)(aRd + (BUF) * 32768 + (H) * 16384 +            \
                               (MG) * 4096 + i_ * 1024);                      \
  } while (0)
#define RDB(BUF, H) do { _Pragma("unroll")                                    \
    for (int j_ = 0; j_ < 4; ++j_)                                            \
      bf[j_] = *(const f16x8*)(bRd + (BUF) * 32768 + (H) * 16384 + j_ * 1024);\
  } while (0)
#define MM(MG) do { _Pragma("unroll")                                         \
    for (int i_ = 0; i_ < 4; ++i_) { _Pragma("unroll")                        \
      for (int j_ = 0; j_ < 4; ++j_)                                          \
        acc[(MG) * 4 + i_][j_] = __builtin_amdgcn_mfma_f32_16x16x32_f16(      \
            af[i_], bf[j_], acc[(MG) * 4 + i_][j_], 0, 0, 0); }               \
  } while (0)
#define PRE_MFMA() do {                                                       \
    __builtin_amdgcn_s_barrier();                                             \
    asm volatile("s_waitcnt lgkmcnt(0)" ::: "memory");                        \
    __builtin_amdgcn_sched_barrier(0);                                        \
  } while (0)

#define TILE(BUF, DOSTAGE, VM2, VM4, LAST) do {                               \
    f16x8 af[4], bf[4];                                                       \
    RDA(BUF, 0, 0); RDB(BUF, 0);                                              \
    if (DOSTAGE) ST_A((BUF) ^ 1, 0);                                          \
    PRE_MFMA();                                                               \
    __builtin_amdgcn_s_setprio(1); MM(0); __builtin_amdgcn_s_setprio(0);      \
    __builtin_amdgcn_s_barrier();                                             \
    RDA(BUF, 0, 1);                                                           \
    if (DOSTAGE) ST_B((BUF) ^ 1, 0);                                          \
    PRE_MFMA();                                                               \
    __builtin_amdgcn_s_setprio(1); MM(1); __builtin_amdgcn_s_setprio(0);      \
    VMW(VM2); __builtin_amdgcn_sched_barrier(0);                              \
    __builtin_amdgcn_s_barrier();                                             \
    RDA(BUF, 1, 0); RDB(BUF, 1);                                              \
    if (DOSTAGE) ST_A((BUF) ^ 1, 1);                                          \
    PRE_MFMA();                                                               \
    __builtin_amdgcn_s_setprio(1); MM(0); __builtin_amdgcn_s_setprio(0);      \
    __builtin_amdgcn_s_barrier();                                             \
    RDA(BUF, 1, 1);                                                           \
    if (DOSTAGE) ST_B((BUF) ^ 1, 1);                                          \
    PRE_MFMA();                                                               \
    __builtin_amdgcn_s_setprio(1); MM(1); __builtin_amdgcn_s_setprio(0);      \
    if (!(LAST)) {                                                            \
      VMW(VM4); __builtin_amdgcn_sched_barrier(0);                            \
      __builtin_amdgcn_s_barrier();                                           \
    }                                                                         \
    if (DOSTAGE) { pA0 += 64; pA1 += 64; pB0 += 64; pB1 += 64; }              \
  } while (0)

  // prologue: tile 0 -> buf 0, order A-h0, B-h0, A-h1, B-h1; first 4 landed
  ST_A(0, 0); ST_B(0, 0); ST_A(0, 1); ST_B(0, 1);
  pA0 += 64; pA1 += 64; pB0 += 64; pB1 += 64;
  VMW(4); __builtin_amdgcn_sched_barrier(0);
  __builtin_amdgcn_s_barrier();

  // tiles 0..13 rolled (buf alternates), t=14 stages tile 15, t=15 drains
#pragma unroll 1
  for (int it = 0; it < 7; ++it) {
    TILE(0, 1, 4, 4, 0);
    TILE(1, 1, 4, 4, 0);
  }
  TILE(0, 1, 4, 4, 0);   // t = 14
  TILE(1, 0, 0, 0, 1);   // t = 15 (no stage; p2 drains to 0; last)

#undef TILE
#undef PRE_MFMA
#undef MM
#undef RDB
#undef RDA
#undef ST_B
#undef ST_A

  // epilogue: fragment C layout col=l16, row=quad*4+r; acc[a][ni] ->
  // row = m0 + wr*128 + a*16 + quad*4 + r, col = n0 + wc*64 + ni*16 + l16
  if (MODE == 1) {
    f16* dst; int nb;
    if (bx < 4)      { dst = (f16*)C0; nb = n0; }
    else if (bx < 8) { dst = (f16*)C1; nb = n0 - 1024; }
    else             { dst = (f16*)C2; nb = n0 - 2048; }
    if (bx < 8) {                            // Q or K: fused RoPE
      float invf[4], sgn[4];
#pragma unroll
      for (int ni = 0; ni < 4; ++ni) {
        int dk = (wc * 64 + ni * 16 + l16) & 63;
        invf[ni] = __builtin_amdgcn_exp2f(-ROPE_L2 * (float)(dk >> 1));
        sgn[ni]  = (dk & 1) ? 1.f : -1.f;
      }
#pragma unroll
      for (int a = 0; a < 8; ++a)
#pragma unroll
        for (int r = 0; r < 4; ++r) {
          int row = m0 + wr * 128 + a * 16 + quad * 4 + r;
          float ps = (float)pos[row & (SEQ - 1)];
#pragma unroll
          for (int ni = 0; ni < 4; ++ni) {
            float ang = ps * invf[ni];
            float c = __cosf(ang), sn = __sinf(ang);
            float v = acc[a][ni][r];
            float p = __shfl_xor(v, 1);
            float ov = fmaf(p * sgn[ni], sn, v * c);
            int col = nb + wc * 64 + ni * 16 + l16;
            dst[(size_t)row * 1024 + col] = (f16)ov;
          }
        }
    } else {                                 // V: plain
#pragma unroll
      for (int a = 0; a < 8; ++a)
#pragma unroll
        for (int ni = 0; ni < 4; ++ni)
#pragma unroll
          for (int r = 0; r < 4; ++r) {
            int row = m0 + wr * 128 + a * 16 + quad * 4 + r;
            int col = nb + wc * 64 + ni * 16 + l16;
            dst[(size_t)row * 1024 + col] = (f16)acc[a][ni][r];
          }
    }
  } else {
    float* dst = (float*)C0;
#pragma unroll
    for (int a = 0; a < 8; ++a)
#pragma unroll
      for (int ni = 0; ni < 4; ++ni)
#pragma unroll
        for (int r = 0; r < 4; ++r) {
          int row = m0 + wr * 128 + a * 16 + quad * 4 + r;
          int col = n0 + wc * 64 + ni * 16 + l16;
          dst[(size_t)row * 1024 + col] = acc[a][ni][r];
        }
  }
}

// ---------------- transposed causal flash attention (unchanged) ----------------
__global__ __launch_bounds__(256, 3) void flash_attn(const f16* __restrict__ Q,
                                                     const f16* __restrict__ Kg,
                                                     const f16* __restrict__ Vg,
                                                     f16* __restrict__ O) {
  __shared__ char smem[38400];
  f16*  KsL         = (f16*)smem;                   // [128][64] key x dk (swizzled), 16 KB
  u32   (*Vt)[67]   = (u32(*)[67])(smem + 16384);   // [64 dk][67 key-pair], 17152 B
  float (*Red0)[66] = (float(*)[66])smem;           // [64 dk][66 q] waves 0,1 (aliases Ks)
  float (*Red1)[66] = (float(*)[66])(smem + 16896); // waves 2,3 (aliases Vt)
  float (*Lb)[17]   = (float(*)[17])(smem + 33792); // [64 q][17], cols 0..15 = wave*4+quad

  const int tid  = threadIdx.x;
  const int bh   = blockIdx.x;
  const int b    = bh >> 4, h = bh & 15;
  const int qblk = 31 - (int)blockIdx.y;          // longest first
  const int q0   = qblk * 64;
  const int wave = tid >> 6, lane = tid & 63;
  const int quad = lane >> 4, l16 = lane & 15;
  const int nkt  = (qblk + 2) >> 1;               // 128-key tiles covering q0+64 keys

  // Q B-frags (pre-scaled by SCALE_LOG2): B[k=dk][n=q] = Q[q=l16][dk=quad*8+j]
  f16x8 qf[4][2];
#pragma unroll
  for (int nt = 0; nt < 4; ++nt)
#pragma unroll
    for (int ks = 0; ks < 2; ++ks) {
      f16x8 qv = *(const f16x8*)(Q + ((size_t)(b * SEQ + q0 + nt * 16 + l16)) * D_MODEL
                                   + h * DKH + ks * 32 + quad * 8);
      qf[nt][ks] = qv * (f16)SCALE_LOG2;
    }

  f32x4 o[4][4];        // O^T partial: [dk-mtile][q-ntile], C layout dk=quad*4+r, q=l16
#pragma unroll
  for (int md = 0; md < 4; ++md)
#pragma unroll
    for (int nt = 0; nt < 4; ++nt) o[md][nt] = (f32x4){0.f, 0.f, 0.f, 0.f};
  float lacc[4] = {0.f, 0.f, 0.f, 0.f};

  const int kp = tid >> 3, dc = (tid & 7) * 8;    // V-transpose staging role

  for (int t = 0; t < nkt; ++t) {
    const int kt = t * 128;
    // V global loads early (keys 2kp,2kp+1 and 64+2kp,65+2kp; dk dc..dc+7)
    const f16* vb = Vg + ((size_t)(b * SEQ + kt + 2 * kp)) * D_MODEL + h * DKH + dc;
    uint4 v0 = *(const uint4*)vb;
    uint4 v1 = *(const uint4*)(vb + D_MODEL);
    uint4 v2 = *(const uint4*)(vb + 64 * D_MODEL);
    uint4 v3 = *(const uint4*)(vb + 65 * D_MODEL);

    if (t) __syncthreads();          // all waves done with prior Ks/Vt
    // K staging via glds16: LDS dest lane-linear, global chunk xor-swizzled
#pragma unroll
    for (int i = 0; i < 4; ++i) {
      int ci = i * 256 + tid;
      int row = ci >> 3, gc = (ci & 7) ^ (row & 7);
      glds16(Kg + ((size_t)(b * SEQ + kt + row)) * D_MODEL + h * DKH + gc * 8,
             smem + (size_t)(i * 256 + (tid & 192)) * 16);
    }
    {  // V transpose: key-pairs packed u32, [dk][kp], stride 67
      union { uint4 u; u16 s[8]; } a0, a1, a2, a3;
      a0.u = v0; a1.u = v1; a2.u = v2; a3.u = v3;
#pragma unroll
      for (int j = 0; j < 8; ++j) {
        Vt[dc + j][kp]      = (u32)a0.s[j] | ((u32)a1.s[j] << 16);
        Vt[dc + j][32 + kp] = (u32)a2.s[j] | ((u32)a3.s[j] << 16);
      }
    }
    __syncthreads();                 // also drains glds vmcnt

    // S^T = K_slice * Q^T (pre-scaled), exp2 -> P^T B-frags (registers only)
    f16x4 pb[2][4];
#pragma unroll
    for (int mt = 0; mt < 2; ++mt) {
      const int krow = wave * 32 + mt * 16 + l16;
      const int s0 = quad ^ (krow & 7);
      f16x8 ka0 = *(const f16x8*)(KsL + krow * 64 + s0 * 8);
      f16x8 ka1 = *(const f16x8*)(KsL + krow * 64 + (s0 ^ 4) * 8);
      const int keyb = kt + wave * 32 + mt * 16 + quad * 4;
#pragma unroll
      for (int nt = 0; nt < 4; ++nt) {
        f32x4 c = (f32x4){0.f, 0.f, 0.f, 0.f};
        c = __builtin_amdgcn_mfma_f32_16x16x32_f16(ka0, qf[nt][0], c, 0, 0, 0);
        c = __builtin_amdgcn_mfma_f32_16x16x32_f16(ka1, qf[nt][1], c, 0, 0, 0);
        const int q = q0 + nt * 16 + l16;
        float p0 = __builtin_amdgcn_exp2f(c[0]);
        float p1 = __builtin_amdgcn_exp2f(c[1]);
        float p2 = __builtin_amdgcn_exp2f(c[2]);
        float p3 = __builtin_amdgcn_exp2f(c[3]);
        if (t == nkt - 1) {          // causal mask (only last tile can clip)
          p0 = (keyb + 0 <= q) ? p0 : 0.f;
          p1 = (keyb + 1 <= q) ? p1 : 0.f;
          p2 = (keyb + 2 <= q) ? p2 : 0.f;
          p3 = (keyb + 3 <= q) ? p3 : 0.f;
        }
        lacc[nt] += (p0 + p1) + (p2 + p3);
        union { u32 w[2]; f16x4 v; } pp;
        pp.w[0] = pk(p0, p1); pp.w[1] = pk(p2, p3);
        pb[mt][nt] = pp.v;
      }
    }

    // O^T += V^T_slice * P^T  (16x16x16_f16, k = 16 keys per step)
#pragma unroll
    for (int md = 0; md < 4; ++md)
#pragma unroll
      for (int ks2 = 0; ks2 < 2; ++ks2) {
        const u32* vp = &Vt[md * 16 + l16][wave * 16 + ks2 * 8 + quad * 2];
        union { u32 x[2]; f16x4 v; } va;
        va.x[0] = vp[0]; va.x[1] = vp[1];
#pragma unroll
        for (int nt = 0; nt < 4; ++nt)
          o[md][nt] = __builtin_amdgcn_mfma_f32_16x16x16f16(va.v, pb[ks2][nt], o[md][nt], 0, 0, 0);
      }
  }

  __syncthreads();
  // cross-wave reduction: wave-pairs {0,1}->Red0, {2,3}->Red1; L fully parallel
  {
    float (*Rw)[66] = (wave >= 2) ? Red1 : Red0;
    if ((wave & 1) == 0) {           // waves 0,2 initialize
#pragma unroll
      for (int md = 0; md < 4; ++md)
#pragma unroll
        for (int nt = 0; nt < 4; ++nt)
#pragma unroll
          for (int r = 0; r < 4; ++r)
            Rw[md * 16 + quad * 4 + r][nt * 16 + l16] = o[md][nt][r];
    }
#pragma unroll
    for (int nt = 0; nt < 4; ++nt)
      Lb[nt * 16 + l16][wave * 4 + quad] = lacc[nt];
    __syncthreads();
    if (wave & 1) {                  // waves 1,3 accumulate
#pragma unroll
      for (int md = 0; md < 4; ++md)
#pragma unroll
        for (int nt = 0; nt < 4; ++nt)
#pragma unroll
          for (int r = 0; r < 4; ++r)
            Rw[md * 16 + quad * 4 + r][nt * 16 + l16] += o[md][nt][r];
    }
    __syncthreads();
  }

  // normalize + store: thread -> (q, 16-dk chunk), 32B contiguous
  {
    const int q = tid & 63, dc4 = (tid >> 6) * 16;
    float lsum = 0.f;
#pragma unroll
    for (int j = 0; j < 16; ++j) lsum += Lb[q][j];
    float linv = __builtin_amdgcn_rcpf(lsum);
    union { uint4 u[2]; u32 w[8]; } ov;
#pragma unroll
    for (int i = 0; i < 8; ++i) {
      float f0 = Red0[dc4 + 2 * i][q]     + Red1[dc4 + 2 * i][q];
      float f1 = Red0[dc4 + 2 * i + 1][q] + Red1[dc4 + 2 * i + 1][q];
      ov.w[i] = pk(f0 * linv, f1 * linv);
    }
    f16* op = O + ((size_t)(b * SEQ + q0 + q)) * D_MODEL + h * DKH + dc4;
    *(uint4*)op = ov.u[0];
    *(uint4*)(op + 8) = ov.u[1];
  }
}

// ---------------- launch ----------------
extern "C" void kernel_launch(void* const* d_in, const int* in_sizes, int n_in,
                              void* d_out, int out_size, void* d_ws, size_t ws_size,
                              hipStream_t stream) {
  const float* x      = (const float*)d_in[0];
  const int*   tokpos = (const int*)d_in[1];
  const float* wq     = (const float*)d_in[2];
  const float* wk     = (const float*)d_in[3];
  const float* wv     = (const float*)d_in[4];
  const float* wo     = (const float*)d_in[5];
  float* out = (float*)d_out;

  char* ws = (char*)d_ws;
  f16* Xb  = (f16*)(ws + 0);           // 16 MB (also Ob)
  f16* Wqb = (f16*)(ws + 16777216);    // Wq,Wk,Wv contiguous -> one [3072][1024]
  f16* Wkb = (f16*)(ws + 18874368);
  f16* Wvb = (f16*)(ws + 20971520);
  f16* Wob = (f16*)(ws + 23068672);
  f16* Qb  = (f16*)(ws + 25165824);
  f16* Kb  = (f16*)(ws + 41943040);
  f16* Vb  = (f16*)(ws + 58720256);
  f16* Ob  = Xb;

  static bool attr_done = false;
  if (!attr_done) {
    auto* f1 = gemm256<1, 48, 12>;
    auto* f0 = gemm256<0, 16, 4>;
    (void)hipFuncSetAttribute(reinterpret_cast<const void*>(f1),
                              hipFuncAttributeMaxDynamicSharedMemorySize, 131072);
    (void)hipFuncSetAttribute(reinterpret_cast<const void*>(f0),
                              hipFuncAttributeMaxDynamicSharedMemorySize, 131072);
    attr_done = true;
  }

  cvt_all<<<12288, 256, 0, stream>>>(x, wq, wk, wv, wo, Xb, Wqb, Wkb, Wvb, Wob);

  // fused QKV projection + RoPE: C[8192,3072] = X * Wqkv^T, split to Qb/Kb/Vb
  gemm256<1, 48, 12><<<384, 512, 131072, stream>>>(Xb, Wqb, Qb, Kb, Vb, tokpos);

  flash_attn<<<dim3(BATCH * NH, 32), 256, 0, stream>>>(Qb, Kb, Vb, Ob);

  gemm256<0, 16, 4><<<128, 512, 131072, stream>>>(Ob, Wob, out, nullptr, nullptr, tokpos);
}

// Round 4
// 246.556 us; speedup vs baseline: 1.0513x; 1.0513x over previous
//
#include <hip/hip_runtime.h>

// multihead self-attention: B=4 S=2048 D=1024 H=16 DK=64, causal, RoPE(theta=1e4)
// f16 pipeline, 4 dispatches:
//   cvt_all | QKV GEMM 256x192 (exact 2 rounds, RoPE fused) | transposed flash |
//   out GEMM 128x256 (exact 1 round)
//
// R4: R0-R3 showed MfmaUtil pinned at 23-28% across four different schedules ->
// limiter is NOT the schedule. OccupancyPercent 14.7% exposed grid quantization:
// QKV 256^2 = 384 blocks = 1.5 rounds (2nd round half-idle); out-GEMM 128 blocks
// = HALF a round. This round keeps R3's 4-phase counted-vmcnt pipeline and fixes
// quantization: QKV BN=192 -> 512 blocks = 2 exact rounds; out BM=128/BN=256 ->
// 256 blocks = 1 exact round. B planes re-swizzled for the new widths
// (store/read permutation matched; 8 lanes x 8 bank-slots = conflict-free).

#define D_MODEL 1024
#define NH      16
#define DKH     64
#define SEQ     2048
#define BATCH   4
#define SCALE_LOG2 0.180336875461f   // (1/sqrt(64)) * log2(e)
#define ROPE_L2    0.41524101186092029f  // log2(1e4)/32

typedef _Float16 f16;
typedef _Float16 f16x8 __attribute__((ext_vector_type(8)));
typedef _Float16 f16x4 __attribute__((ext_vector_type(4)));
typedef __fp16   fp16x2n __attribute__((ext_vector_type(2)));
typedef float    f32x4 __attribute__((ext_vector_type(4)));
typedef unsigned short u16;
typedef unsigned int   u32;

__device__ __forceinline__ void glds16(const void* g, void* l) {
  __builtin_amdgcn_global_load_lds((const __attribute__((address_space(1))) void*)g,
                                   (__attribute__((address_space(3))) void*)l, 16, 0, 0);
}
__device__ __forceinline__ u32 pk(float a, float b) {
  union { fp16x2n h; u32 u; } c; c.h = __builtin_amdgcn_cvt_pkrtz(a, b); return c.u;
}

#define VMW_(N) asm volatile("s_waitcnt vmcnt(" #N ")" ::: "memory")
#define VMW(N) VMW_(N)
#define PRE_MFMA() do {                                                       \
    __builtin_amdgcn_s_barrier();                                             \
    asm volatile("s_waitcnt lgkmcnt(0)" ::: "memory");                        \
    __builtin_amdgcn_sched_barrier(0);                                        \
  } while (0)

// ---------------- f32 -> f16 convert: x (8192 blocks) + 4 weights (1024 each) ----
__global__ void cvt_all(const float* __restrict__ x,
                        const float* __restrict__ w0, const float* __restrict__ w1,
                        const float* __restrict__ w2, const float* __restrict__ w3,
                        f16* __restrict__ xo, f16* __restrict__ o0, f16* __restrict__ o1,
                        f16* __restrict__ o2, f16* __restrict__ o3) {
  int blk = blockIdx.x;
  const float* src; f16* dst; int off;
  if (blk < 8192) { src = x; dst = xo; off = blk; }
  else {
    int t = blk - 8192; int w = t >> 10; off = t & 1023;
    switch (w) { case 0: src = w0; dst = o0; break;  case 1: src = w1; dst = o1; break;
                 case 2: src = w2; dst = o2; break;  default: src = w3; dst = o3; break; }
  }
  int i = (off * 256 + threadIdx.x) * 4;
  float4 v = *(const float4*)(src + i);
  uint2 o; o.x = pk(v.x, v.y); o.y = pk(v.z, v.w);
  *(uint2*)(dst + i) = o;
}

// ---- QKV GEMM: C[8192,3072] = X[8192,1024] * W[3072,1024]^T, BM=256 BN=192 ----
// grid 512 = 32 row-blocks x 16 col-blocks = 2 exact rounds of 256 CUs.
// LDS 114688 B: A planes (buf,h) 16 KB at buf*32768+h*16384 (64 KB total);
// B planes (buf) 24 KB at 65536+buf*24576 (192 rows x 8 chunks, full BK).
// A layout (as R3, verified 0-conflict): chunk L = sr*8+(r&1)*4+(c^(sr&3)).
// B layout: LDS chunk (r,p) holds global chunk p^(r&7); read pos
// (h*4+quad)^(l16&7) -> 8 lanes per bank-slot over 8 slots = conflict-free.
// Schedule per tile (buf b, 4 phases, 12 MFMA each):
//  p1: rd A(b,h0,mg0)+B(b,h0); stage A(b^1,h0)[2]; bar;lgkm0;MFMA;bar
//  p2: rd A(b,h0,mg1);         stage B(b^1)[3];    bar;lgkm0;MFMA;vmcnt(5);bar
//  p3: rd A(b,h1,mg0)+B(b,h1); stage A(b^1,h1)[2]; bar;lgkm0;MFMA;bar
//  p4: rd A(b,h1,mg1);                             bar;lgkm0;MFMA;vmcnt(2);bar
// Steady: 7 glds/tile in flight max; vmcnt(5)=A(b,h1) landed, vmcnt(2)=next
// tile's A-h0+B landed. Tail t15: p2-wait vmcnt(0), p4 last (no wait).
__global__ __launch_bounds__(512, 2) void gemm_qkv(const f16* __restrict__ A,
                                                   const f16* __restrict__ W,
                                                   f16* __restrict__ Qo,
                                                   f16* __restrict__ Ko,
                                                   f16* __restrict__ Vo,
                                                   const int* __restrict__ pos) {
  extern __shared__ char lds[];
  const int bid  = blockIdx.x;
  const int lin  = (bid & 7) * 64 + (bid >> 3);    // bijective XCD swizzle (512=8x64)
  const int bx   = lin & 15, by = lin >> 4;
  const int m0   = by * 256, n0 = bx * 192;
  const int tid  = threadIdx.x;
  const int wave = tid >> 6, lane = tid & 63;
  const int quad = lane >> 4, l16 = lane & 15;
  const int wr   = wave >> 2, wc = wave & 3;       // wave tile: rows wr*128, cols wc*48

  f32x4 acc[8][3];
#pragma unroll
  for (int i = 0; i < 8; ++i)
#pragma unroll
    for (int j = 0; j < 3; ++j) acc[i][j] = (f32x4){0.f, 0.f, 0.f, 0.f};

  // read bases (per-thread constant; all ds offsets compile-time imm)
  const int posR = (l16 & 1) * 4 + (quad ^ ((l16 >> 1) & 3));
  const char* aRd  = lds + wr * 8192 + (l16 >> 1) * 128 + posR * 16;
  const char* bRd0 = lds + 65536 + (wc * 48 + l16) * 128 + ((quad) ^ (l16 & 7)) * 16;
  const char* bRd1 = lds + 65536 + (wc * 48 + l16) * 128 + ((4 + quad) ^ (l16 & 7)) * 16;

  // A staging (2 glds/thread): plane chunks L0=tid, L1=tid+512
  const int srA = tid >> 3;
  const int rA  = 2 * srA + ((tid >> 2) & 1);
  const int cA  = (tid & 3) ^ (srA & 3);
  const f16* pA0 = A + (size_t)(m0 + rA) * 1024 + cA * 8;
  const f16* pA1 = pA0 + (size_t)128 * 1024;
  // B staging (3 glds/thread): chunks ci = i*512+tid; row=i*64+(tid>>3), g const
  const int gB = (tid & 7) ^ ((tid >> 3) & 7);
  const f16* pB0 = W + (size_t)(n0 + (tid >> 3)) * 1024 + gB * 8;
  const f16* pB1 = pB0 + (size_t)64 * 1024;
  const f16* pB2 = pB0 + (size_t)128 * 1024;
  char* const sdA = lds + (size_t)(tid & 448) * 16;
  char* const sdB = lds + 65536 + (size_t)(tid & 448) * 16;

#define ST_A(TB, H) do {                                                      \
    glds16(pA0 + (H) * 32, sdA + (TB) * 32768 + (H) * 16384);                 \
    glds16(pA1 + (H) * 32, sdA + (TB) * 32768 + (H) * 16384 + 8192);          \
  } while (0)
#define ST_B(TB) do {                                                         \
    glds16(pB0, sdB + (TB) * 24576);                                          \
    glds16(pB1, sdB + (TB) * 24576 + 8192);                                   \
    glds16(pB2, sdB + (TB) * 24576 + 16384);                                  \
  } while (0)
#define RDA(BUF, H, MG) do { _Pragma("unroll")                                \
    for (int i_ = 0; i_ < 4; ++i_)                                            \
      af[i_] = *(const f16x8*)(aRd + (BUF) * 32768 + (H) * 16384 +            \
                               (MG) * 4096 + i_ * 1024);                      \
  } while (0)
#define RDB(BUF, H) do { _Pragma("unroll")                                    \
    for (int j_ = 0; j_ < 3; ++j_)                                            \
      bf[j_] = *(const f16x8*)(((H) ? bRd1 : bRd0) + (BUF) * 24576 + j_ * 2048);\
  } while (0)
#define MMQ(MG) do {                                                          \
    __builtin_amdgcn_s_setprio(1);                                            \
    _Pragma("unroll")                                                         \
    for (int i_ = 0; i_ < 4; ++i_) { _Pragma("unroll")                        \
      for (int j_ = 0; j_ < 3; ++j_)                                          \
        acc[(MG) * 4 + i_][j_] = __builtin_amdgcn_mfma_f32_16x16x32_f16(      \
            af[i_], bf[j_], acc[(MG) * 4 + i_][j_], 0, 0, 0); }               \
    __builtin_amdgcn_s_setprio(0);                                            \
  } while (0)

#define TILE(BUF, DOSTAGE, VM2, LAST) do {                                    \
    f16x8 af[4]; f16x8 bf[3];                                                 \
    RDA(BUF, 0, 0); RDB(BUF, 0);                                              \
    if (DOSTAGE) ST_A((BUF) ^ 1, 0);                                          \
    PRE_MFMA(); MMQ(0);                                                       \
    __builtin_amdgcn_s_barrier();                                             \
    RDA(BUF, 0, 1);                                                           \
    if (DOSTAGE) ST_B((BUF) ^ 1);                                             \
    PRE_MFMA(); MMQ(1);                                                       \
    VMW(VM2); __builtin_amdgcn_sched_barrier(0);                              \
    __builtin_amdgcn_s_barrier();                                             \
    RDA(BUF, 1, 0); RDB(BUF, 1);                                              \
    if (DOSTAGE) ST_A((BUF) ^ 1, 1);                                          \
    PRE_MFMA(); MMQ(0);                                                       \
    __builtin_amdgcn_s_barrier();                                             \
    RDA(BUF, 1, 1);                                                           \
    PRE_MFMA(); MMQ(1);                                                       \
    if (!(LAST)) {                                                            \
      VMW_(2); __builtin_amdgcn_sched_barrier(0);                             \
      __builtin_amdgcn_s_barrier();                                           \
    }                                                                         \
    if (DOSTAGE) { pA0 += 64; pA1 += 64; pB0 += 64; pB1 += 64; pB2 += 64; }   \
  } while (0)

  // prologue: tile0 A-h0(2), B(3), A-h1(2); first 5 landed
  ST_A(0, 0); ST_B(0); ST_A(0, 1);
  pA0 += 64; pA1 += 64; pB0 += 64; pB1 += 64; pB2 += 64;
  VMW_(2); __builtin_amdgcn_sched_barrier(0);
  __builtin_amdgcn_s_barrier();

#pragma unroll 1
  for (int it = 0; it < 7; ++it) {
    TILE(0, 1, 5, 0);
    TILE(1, 1, 5, 0);
  }
  TILE(0, 1, 5, 0);   // t = 14, stages tile 15
  TILE(1, 0, 0, 1);   // t = 15: no stage; p2 drains to 0; last

#undef TILE
#undef MMQ
#undef RDB
#undef RDA
#undef ST_B
#undef ST_A

  // epilogue: frag C layout col=l16, row=quad*4+r. 192-wide tiles cross Q/K/V
  // boundaries -> resolve segment per 16-col frag (wave-uniform per ni).
  f16* dsts[3]; int colB[3]; bool rp[3]; float invf[3], sgn[3];
#pragma unroll
  for (int ni = 0; ni < 3; ++ni) {
    int gc  = n0 + wc * 48 + ni * 16 + l16;
    int seg = gc >> 10;
    dsts[ni] = (seg == 0) ? Qo : (seg == 1) ? Ko : Vo;
    colB[ni] = gc & 1023;
    rp[ni]   = (seg < 2);
    int dk   = gc & 63;
    invf[ni] = __builtin_amdgcn_exp2f(-ROPE_L2 * (float)(dk >> 1));
    sgn[ni]  = (dk & 1) ? 1.f : -1.f;
  }
#pragma unroll
  for (int a = 0; a < 8; ++a)
#pragma unroll
    for (int r = 0; r < 4; ++r) {
      int row = m0 + wr * 128 + a * 16 + quad * 4 + r;
      float ps = (float)pos[row & (SEQ - 1)];
#pragma unroll
      for (int ni = 0; ni < 3; ++ni) {
        float v = acc[a][ni][r];
        float ov;
        if (rp[ni]) {                        // Q or K: fused RoPE
          float ang = ps * invf[ni];
          float c = __cosf(ang), sn = __sinf(ang);
          float p = __shfl_xor(v, 1);
          ov = fmaf(p * sgn[ni], sn, v * c);
        } else ov = v;                       // V: plain
        dsts[ni][(size_t)row * 1024 + colB[ni]] = (f16)ov;
      }
    }
}

// ---- out GEMM: C[8192,1024] = O[8192,1024] * Wo[1024,1024]^T, BM=128 BN=256 ----
// grid 256 = 64 row-blocks x 4 col-blocks = 1 exact round.
// LDS 98304 B: A planes (buf,h) 8 KB at buf*16384+h*8192 (32 KB);
// B planes (buf,h) 16 KB at 32768+buf*32768+h*16384 (64 KB). Layouts as R3.
// 2 phases/tile (16 MFMA each), uniform issue-3/wait-vmcnt(3) pipeline.
__global__ __launch_bounds__(512, 2) void gemm_out(const f16* __restrict__ A,
                                                   const f16* __restrict__ W,
                                                   float* __restrict__ C) {
  extern __shared__ char lds[];
  const int bid  = blockIdx.x;
  const int lin  = (bid & 7) * 32 + (bid >> 3);    // bijective (256=8x32)
  const int bx   = lin & 3, by = lin >> 2;
  const int m0   = by * 128, n0 = bx * 256;
  const int tid  = threadIdx.x;
  const int wave = tid >> 6, lane = tid & 63;
  const int quad = lane >> 4, l16 = lane & 15;
  const int wr   = wave >> 2, wc = wave & 3;       // rows wr*64, cols wc*64

  f32x4 acc[4][4];
#pragma unroll
  for (int i = 0; i < 4; ++i)
#pragma unroll
    for (int j = 0; j < 4; ++j) acc[i][j] = (f32x4){0.f, 0.f, 0.f, 0.f};

  const int posR = (l16 & 1) * 4 + (quad ^ ((l16 >> 1) & 3));
  const char* aRd = lds + wr * 4096 + (l16 >> 1) * 128 + posR * 16;
  const char* bRd = lds + 32768 + wc * 4096 + (l16 >> 1) * 128 + posR * 16;

  // A staging (1 glds/thread): 512-chunk plane, L=tid
  const int srA = tid >> 3;
  const int rA  = 2 * srA + ((tid >> 2) & 1);
  const int cA  = (tid & 3) ^ (srA & 3);
  const f16* pA = A + (size_t)(m0 + rA) * 1024 + cA * 8;
  // B staging (2 glds/thread): 1024-chunk plane, L0=tid, L1=tid+512
  const int rB  = 2 * (tid >> 3) + ((tid >> 2) & 1);
  const int cB  = (tid & 3) ^ ((tid >> 3) & 3);
  const f16* pB0 = W + (size_t)(n0 + rB) * 1024 + cB * 8;
  const f16* pB1 = pB0 + (size_t)128 * 1024;
  char* const sdA = lds + (size_t)(tid & 448) * 16;
  char* const sdB = lds + 32768 + (size_t)(tid & 448) * 16;

#define ST_AO(TB, H) glds16(pA + (H) * 32, sdA + (TB) * 16384 + (H) * 8192)
#define ST_BO(TB, H) do {                                                     \
    glds16(pB0 + (H) * 32, sdB + (TB) * 32768 + (H) * 16384);                 \
    glds16(pB1 + (H) * 32, sdB + (TB) * 32768 + (H) * 16384 + 8192);          \
  } while (0)
#define HALF(BUF, H, DOSTAGE, VMN, LAST) do {                                 \
    f16x8 af[4], bf[4];                                                       \
    _Pragma("unroll")                                                         \
    for (int i_ = 0; i_ < 4; ++i_)                                            \
      af[i_] = *(const f16x8*)(aRd + (BUF) * 16384 + (H) * 8192 + i_ * 1024); \
    _Pragma("unroll")                                                         \
    for (int j_ = 0; j_ < 4; ++j_)                                            \
      bf[j_] = *(const f16x8*)(bRd + (BUF) * 32768 + (H) * 16384 + j_ * 1024);\
    if (DOSTAGE) { ST_AO((BUF) ^ 1, H); ST_BO((BUF) ^ 1, H); }                \
    PRE_MFMA();                                                               \
    __builtin_amdgcn_s_setprio(1);                                            \
    _Pragma("unroll")                                                         \
    for (int i_ = 0; i_ < 4; ++i_) { _Pragma("unroll")                        \
      for (int j_ = 0; j_ < 4; ++j_)                                          \
        acc[i_][j_] = __builtin_amdgcn_mfma_f32_16x16x32_f16(                 \
            af[i_], bf[j_], acc[i_][j_], 0, 0, 0); }                          \
    __builtin_amdgcn_s_setprio(0);                                            \
    if (!(LAST)) {                                                            \
      VMW(VMN); __builtin_amdgcn_sched_barrier(0);                            \
      __builtin_amdgcn_s_barrier();                                           \
    }                                                                         \
  } while (0)

  // prologue: tile0 h0-group(3), h1-group(3); first 3 landed
  ST_AO(0, 0); ST_BO(0, 0); ST_AO(0, 1); ST_BO(0, 1);
  pA += 64; pB0 += 64; pB1 += 64;
  VMW_(3); __builtin_amdgcn_sched_barrier(0);
  __builtin_amdgcn_s_barrier();

#pragma unroll 1
  for (int it = 0; it < 7; ++it) {
    HALF(0, 0, 1, 3, 0); HALF(0, 1, 1, 3, 0); pA += 64; pB0 += 64; pB1 += 64;
    HALF(1, 0, 1, 3, 0); HALF(1, 1, 1, 3, 0); pA += 64; pB0 += 64; pB1 += 64;
  }
  HALF(0, 0, 1, 3, 0); HALF(0, 1, 1, 3, 0);   // t = 14, stages tile 15
  HALF(1, 0, 0, 0, 0);                         // t = 15 p1: drain to 0
  HALF(1, 1, 0, 0, 1);                         // t = 15 p2: last

#undef HALF
#undef ST_BO
#undef ST_AO

  float* dst = C;
#pragma unroll
  for (int a = 0; a < 4; ++a)
#pragma unroll
    for (int ni = 0; ni < 4; ++ni)
#pragma unroll
      for (int r = 0; r < 4; ++r) {
        int row = m0 + wr * 64 + a * 16 + quad * 4 + r;
        int col = n0 + wc * 64 + ni * 16 + l16;
        dst[(size_t)row * 1024 + col] = acc[a][ni][r];
      }
}

// ---------------- transposed causal flash attention (unchanged) ----------------
__global__ __launch_bounds__(256, 3) void flash_attn(const f16* __restrict__ Q,
                                                     const f16* __restrict__ Kg,
                                                     const f16* __restrict__ Vg,
                                                     f16* __restrict__ O) {
  __shared__ char smem[38400];
  f16*  KsL         = (f16*)smem;                   // [128][64] key x dk (swizzled), 16 KB
  u32   (*Vt)[67]   = (u32(*)[67])(smem + 16384);   // [64 dk][67 key-pair], 17152 B
  float (*Red0)[66] = (float(*)[66])smem;           // [64 dk][66 q] waves 0,1 (aliases Ks)
  float (*Red1)[66] = (float(*)[66])(smem + 16896); // waves 2,3 (aliases Vt)
  float (*Lb)[17]   = (float(*)[17])(smem + 33792); // [64 q][17], cols 0..15 = wave*4+quad

  const int tid  = threadIdx.x;
  const int bh   = blockIdx.x;
  const int b    = bh >> 4, h = bh & 15;
  const int qblk = 31 - (int)blockIdx.y;          // longest first
  const int q0   = qblk * 64;
  const int wave = tid >> 6, lane = tid & 63;
  const int quad = lane >> 4, l16 = lane & 15;
  const int nkt  = (qblk + 2) >> 1;               // 128-key tiles covering q0+64 keys

  // Q B-frags (pre-scaled by SCALE_LOG2): B[k=dk][n=q] = Q[q=l16][dk=quad*8+j]
  f16x8 qf[4][2];
#pragma unroll
  for (int nt = 0; nt < 4; ++nt)
#pragma unroll
    for (int ks = 0; ks < 2; ++ks) {
      f16x8 qv = *(const f16x8*)(Q + ((size_t)(b * SEQ + q0 + nt * 16 + l16)) * D_MODEL
                                   + h * DKH + ks * 32 + quad * 8);
      qf[nt][ks] = qv * (f16)SCALE_LOG2;
    }

  f32x4 o[4][4];        // O^T partial: [dk-mtile][q-ntile], C layout dk=quad*4+r, q=l16
#pragma unroll
  for (int md = 0; md < 4; ++md)
#pragma unroll
    for (int nt = 0; nt < 4; ++nt) o[md][nt] = (f32x4){0.f, 0.f, 0.f, 0.f};
  float lacc[4] = {0.f, 0.f, 0.f, 0.f};

  const int kp = tid >> 3, dc = (tid & 7) * 8;    // V-transpose staging role

  for (int t = 0; t < nkt; ++t) {
    const int kt = t * 128;
    // V global loads early (keys 2kp,2kp+1 and 64+2kp,65+2kp; dk dc..dc+7)
    const f16* vb = Vg + ((size_t)(b * SEQ + kt + 2 * kp)) * D_MODEL + h * DKH + dc;
    uint4 v0 = *(const uint4*)vb;
    uint4 v1 = *(const uint4*)(vb + D_MODEL);
    uint4 v2 = *(const uint4*)(vb + 64 * D_MODEL);
    uint4 v3 = *(const uint4*)(vb + 65 * D_MODEL);

    if (t) __syncthreads();          // all waves done with prior Ks/Vt
    // K staging via glds16: LDS dest lane-linear, global chunk xor-swizzled
#pragma unroll
    for (int i = 0; i < 4; ++i) {
      int ci = i * 256 + tid;
      int row = ci >> 3, gc = (ci & 7) ^ (row & 7);
      glds16(Kg + ((size_t)(b * SEQ + kt + row)) * D_MODEL + h * DKH + gc * 8,
             smem + (size_t)(i * 256 + (tid & 192)) * 16);
    }
    {  // V transpose: key-pairs packed u32, [dk][kp], stride 67
      union { uint4 u; u16 s[8]; } a0, a1, a2, a3;
      a0.u = v0; a1.u = v1; a2.u = v2; a3.u = v3;
#pragma unroll
      for (int j = 0; j < 8; ++j) {
        Vt[dc + j][kp]      = (u32)a0.s[j] | ((u32)a1.s[j] << 16);
        Vt[dc + j][32 + kp] = (u32)a2.s[j] | ((u32)a3.s[j] << 16);
      }
    }
    __syncthreads();                 // also drains glds vmcnt

    // S^T = K_slice * Q^T (pre-scaled), exp2 -> P^T B-frags (registers only)
    f16x4 pb[2][4];
#pragma unroll
    for (int mt = 0; mt < 2; ++mt) {
      const int krow = wave * 32 + mt * 16 + l16;
      const int s0 = quad ^ (krow & 7);
      f16x8 ka0 = *(const f16x8*)(KsL + krow * 64 + s0 * 8);
      f16x8 ka1 = *(const f16x8*)(KsL + krow * 64 + (s0 ^ 4) * 8);
      const int keyb = kt + wave * 32 + mt * 16 + quad * 4;
#pragma unroll
      for (int nt = 0; nt < 4; ++nt) {
        f32x4 c = (f32x4){0.f, 0.f, 0.f, 0.f};
        c = __builtin_amdgcn_mfma_f32_16x16x32_f16(ka0, qf[nt][0], c, 0, 0, 0);
        c = __builtin_amdgcn_mfma_f32_16x16x32_f16(ka1, qf[nt][1], c, 0, 0, 0);
        const int q = q0 + nt * 16 + l16;
        float p0 = __builtin_amdgcn_exp2f(c[0]);
        float p1 = __builtin_amdgcn_exp2f(c[1]);
        float p2 = __builtin_amdgcn_exp2f(c[2]);
        float p3 = __builtin_amdgcn_exp2f(c[3]);
        if (t == nkt - 1) {          // causal mask (only last tile can clip)
          p0 = (keyb + 0 <= q) ? p0 : 0.f;
          p1 = (keyb + 1 <= q) ? p1 : 0.f;
          p2 = (keyb + 2 <= q) ? p2 : 0.f;
          p3 = (keyb + 3 <= q) ? p3 : 0.f;
        }
        lacc[nt] += (p0 + p1) + (p2 + p3);
        union { u32 w[2]; f16x4 v; } pp;
        pp.w[0] = pk(p0, p1); pp.w[1] = pk(p2, p3);
        pb[mt][nt] = pp.v;
      }
    }

    // O^T += V^T_slice * P^T  (16x16x16_f16, k = 16 keys per step)
#pragma unroll
    for (int md = 0; md < 4; ++md)
#pragma unroll
      for (int ks2 = 0; ks2 < 2; ++ks2) {
        const u32* vp = &Vt[md * 16 + l16][wave * 16 + ks2 * 8 + quad * 2];
        union { u32 x[2]; f16x4 v; } va;
        va.x[0] = vp[0]; va.x[1] = vp[1];
#pragma unroll
        for (int nt = 0; nt < 4; ++nt)
          o[md][nt] = __builtin_amdgcn_mfma_f32_16x16x16f16(va.v, pb[ks2][nt], o[md][nt], 0, 0, 0);
      }
  }

  __syncthreads();
  // cross-wave reduction: wave-pairs {0,1}->Red0, {2,3}->Red1; L fully parallel
  {
    float (*Rw)[66] = (wave >= 2) ? Red1 : Red0;
    if ((wave & 1) == 0) {           // waves 0,2 initialize
#pragma unroll
      for (int md = 0; md < 4; ++md)
#pragma unroll
        for (int nt = 0; nt < 4; ++nt)
#pragma unroll
          for (int r = 0; r < 4; ++r)
            Rw[md * 16 + quad * 4 + r][nt * 16 + l16] = o[md][nt][r];
    }
#pragma unroll
    for (int nt = 0; nt < 4; ++nt)
      Lb[nt * 16 + l16][wave * 4 + quad] = lacc[nt];
    __syncthreads();
    if (wave & 1) {                  // waves 1,3 accumulate
#pragma unroll
      for (int md = 0; md < 4; ++md)
#pragma unroll
        for (int nt = 0; nt < 4; ++nt)
#pragma unroll
          for (int r = 0; r < 4; ++r)
            Rw[md * 16 + quad * 4 + r][nt * 16 + l16] += o[md][nt][r];
    }
    __syncthreads();
  }

  // normalize + store: thread -> (q, 16-dk chunk), 32B contiguous
  {
    const int q = tid & 63, dc4 = (tid >> 6) * 16;
    float lsum = 0.f;
#pragma unroll
    for (int j = 0; j < 16; ++j) lsum += Lb[q][j];
    float linv = __builtin_amdgcn_rcpf(lsum);
    union { uint4 u[2]; u32 w[8]; } ov;
#pragma unroll
    for (int i = 0; i < 8; ++i) {
      float f0 = Red0[dc4 + 2 * i][q]     + Red1[dc4 + 2 * i][q];
      float f1 = Red0[dc4 + 2 * i + 1][q] + Red1[dc4 + 2 * i + 1][q];
      ov.w[i] = pk(f0 * linv, f1 * linv);
    }
    f16* op = O + ((size_t)(b * SEQ + q0 + q)) * D_MODEL + h * DKH + dc4;
    *(uint4*)op = ov.u[0];
    *(uint4*)(op + 8) = ov.u[1];
  }
}

// ---------------- launch ----------------
extern "C" void kernel_launch(void* const* d_in, const int* in_sizes, int n_in,
                              void* d_out, int out_size, void* d_ws, size_t ws_size,
                              hipStream_t stream) {
  const float* x      = (const float*)d_in[0];
  const int*   tokpos = (const int*)d_in[1];
  const float* wq     = (const float*)d_in[2];
  const float* wk     = (const float*)d_in[3];
  const float* wv     = (const float*)d_in[4];
  const float* wo     = (const float*)d_in[5];
  float* out = (float*)d_out;

  char* ws = (char*)d_ws;
  f16* Xb  = (f16*)(ws + 0);           // 16 MB (also Ob)
  f16* Wqb = (f16*)(ws + 16777216);    // Wq,Wk,Wv contiguous -> one [3072][1024]
  f16* Wkb = (f16*)(ws + 18874368);
  f16* Wvb = (f16*)(ws + 20971520);
  f16* Wob = (f16*)(ws + 23068672);
  f16* Qb  = (f16*)(ws + 25165824);
  f16* Kb  = (f16*)(ws + 41943040);
  f16* Vb  = (f16*)(ws + 58720256);
  f16* Ob  = Xb;

  static bool attr_done = false;
  if (!attr_done) {
    (void)hipFuncSetAttribute(reinterpret_cast<const void*>(gemm_qkv),
                              hipFuncAttributeMaxDynamicSharedMemorySize, 114688);
    (void)hipFuncSetAttribute(reinterpret_cast<const void*>(gemm_out),
                              hipFuncAttributeMaxDynamicSharedMemorySize, 98304);
    attr_done = true;
  }

  cvt_all<<<12288, 256, 0, stream>>>(x, wq, wk, wv, wo, Xb, Wqb, Wkb, Wvb, Wob);

  // fused QKV projection + RoPE: C[8192,3072] = X * Wqkv^T, split to Qb/Kb/Vb
  gemm_qkv<<<512, 512, 114688, stream>>>(Xb, Wqb, Qb, Kb, Vb, tokpos);

  flash_attn<<<dim3(BATCH * NH, 32), 256, 0, stream>>>(Qb, Kb, Vb, Ob);

  gemm_out<<<256, 512, 98304, stream>>>(Ob, Wob, out);
}